// Round 2
// baseline (429.567 us; speedup 1.0000x reference)
//
#include <hip/hip_runtime.h>
#include <math.h>

// LogPolar resample: data [32,3,512,512] f32 -> out [32,3,512,512] f32.
// Map depends only on output pixel => 1 thread per pixel, loop over the
// 96 (batch*channel) images. Memory-bound; floor ~32us at 6.3 TB/s.

constexpr int H_IN  = 512;
constexpr int W_IN  = 512;
constexpr int H_OUT = 512;
constexpr int W_OUT = 512;
constexpr int BC    = 32 * 3;          // batch * channels
constexpr int IMG   = H_IN * W_IN;     // elements per image plane
constexpr int NPIX  = H_OUT * W_OUT;

__global__ __launch_bounds__(256) void logpolar_kernel(
    const float* __restrict__ data, float* __restrict__ out)
{
    const int pix = blockIdx.x * blockDim.x + threadIdx.x;  // 0..262143
    if (pix >= NPIX) return;
    const int i = pix >> 9;            // theta index (output row)
    const int j = pix & (W_OUT - 1);   // r index (output col)

    // max_r = np.float32(log(norm([512,512])/2 * 2.0)): computed in double,
    // then cast to f32 — value below is the f64 result; f32 cast is exact here.
    const float max_r = (float)6.584898215319481;

    // Mirror reference f32 op order: (theta*2*pi)/H_OUT ; (r*max_r)/W_OUT
    const float theta  = ((float)(2 * i) * 3.14159274101257324f) / (float)H_OUT;
    const float radius = expf(((float)j * max_r) / (float)W_OUT);
    const float X = 256.0f + radius * cosf(theta);   // center_x + X0
    const float Y = 256.0f - radius * sinf(theta);   // center_y - Y0

    float* q = out + pix;

    const bool in_bounds =
        (X >= 0.0f) && (X < (float)H_IN) && (Y >= 0.0f) && (Y < (float)W_IN);

    if (!in_bounds) {
        // mask == 0: reference multiplies the blend by 0 (inputs finite) -> exact 0.
        #pragma unroll 8
        for (int bc = 0; bc < BC; ++bc) {
            *q = 0.0f;
            q += IMG;
        }
        return;
    }

    // trunc-toward-zero (X,Y >= 0 here); in-bounds => already within [0,511].
    const int y_down = (int)Y;
    const int x_down = (int)X;
    const int y_up = min(y_down + 1, H_IN - 1);
    const int x_up = min(x_down + 1, W_IN - 1);

    const float yd = Y - (float)y_down;
    const float yu = Y - (float)y_up;
    const float xd = X - (float)x_down;
    const float xu = X - (float)x_up;

    const float dd = yd * yd + xd * xd;
    const float du = yd * yd + xu * xu;
    const float ud = yu * yu + xd * xd;
    const float uu = yu * yu + xu * xu;
    const float total = ((dd + du) + ud) + uu;

    const float wdd = dd / total;
    const float wdu = du / total;
    const float wud = ud / total;
    const float wuu = uu / total;

    const int o_dd = y_down * W_IN + x_down;
    const int o_du = y_down * W_IN + x_up;
    const int o_ud = y_up * W_IN + x_down;
    const int o_uu = y_up * W_IN + x_up;

    const float* p = data;
    #pragma unroll 4
    for (int bc = 0; bc < BC; ++bc) {
        const float g1 = p[o_dd];
        const float g2 = p[o_du];
        const float g3 = p[o_ud];
        const float g4 = p[o_uu];
        *q = ((wdd * g1 + wdu * g2) + wud * g3) + wuu * g4;
        p += IMG;
        q += IMG;
    }
}

extern "C" void kernel_launch(void* const* d_in, const int* in_sizes, int n_in,
                              void* d_out, int out_size, void* d_ws, size_t ws_size,
                              hipStream_t stream)
{
    const float* data = (const float*)d_in[0];
    float* out = (float*)d_out;

    const int threads = 256;
    const int blocks = (NPIX + threads - 1) / threads;  // 1024
    logpolar_kernel<<<blocks, threads, 0, stream>>>(data, out);
}

// Round 4
// 290.335 us; speedup vs baseline: 1.4796x; 1.4796x over previous
//
#include <hip/hip_runtime.h>
#include <math.h>

// LogPolar resample: data [32,3,512,512] f32 -> out [32,3,512,512] f32.
// Map depends only on output pixel. Round-2 counters showed latency-bound
// (occupancy 16.5%, HBM 18%, VALU 2.5%) + 3.25x input over-fetch (per-XCD L2
// each re-fetching every image). Fix: split the 96-image loop into 8 chunks
// of 12 across blockIdx (8x TLP), with chunk = blockIdx & 7 so each chunk is
// pinned to one XCD's L2 (consecutive blocks round-robin XCDs).

constexpr int H_IN  = 512;
constexpr int W_IN  = 512;
constexpr int H_OUT = 512;
constexpr int W_OUT = 512;
constexpr int BC    = 32 * 3;          // batch * channels
constexpr int IMG   = H_IN * W_IN;     // elements per image plane
constexpr int NPIX  = H_OUT * W_OUT;
constexpr int NCHUNK = 8;              // = #XCDs
constexpr int IMGS_PER_CHUNK = BC / NCHUNK;  // 12

__global__ __launch_bounds__(256) void logpolar_kernel(
    const float* __restrict__ data, float* __restrict__ out)
{
    // chunk pinned to XCD: blocks dispatch round-robin across the 8 XCDs,
    // so blockIdx.x & 7 keeps all of one image-chunk's gathers in one L2.
    const int chunk  = blockIdx.x & (NCHUNK - 1);
    const int pixblk = blockIdx.x >> 3;
    const int pix = pixblk * blockDim.x + threadIdx.x;  // 0..262143
    if (pix >= NPIX) return;
    const int i = pix >> 9;            // theta index (output row)
    const int j = pix & (W_OUT - 1);   // r index (output col)

    // max_r = np.float32(log(norm([512,512])/2 * 2.0)) — f64 value, exact cast.
    const float max_r = (float)6.584898215319481;

    // Mirror reference f32 op order: (theta*2*pi)/H_OUT ; (r*max_r)/W_OUT
    const float theta  = ((float)(2 * i) * 3.14159274101257324f) / (float)H_OUT;
    const float radius = expf(((float)j * max_r) / (float)W_OUT);
    const float X = 256.0f + radius * cosf(theta);   // center_x + X0
    const float Y = 256.0f - radius * sinf(theta);   // center_y - Y0

    const float* p = data + (size_t)chunk * IMGS_PER_CHUNK * IMG;
    float*       q = out  + (size_t)chunk * IMGS_PER_CHUNK * IMG + pix;

    const bool in_bounds =
        (X >= 0.0f) && (X < (float)H_IN) && (Y >= 0.0f) && (Y < (float)W_IN);

    if (!in_bounds) {
        // mask == 0: reference multiplies the blend by 0 (inputs finite) -> exact 0.
        #pragma unroll
        for (int bc = 0; bc < IMGS_PER_CHUNK; ++bc) {
            *q = 0.0f;
            q += IMG;
        }
        return;
    }

    // trunc-toward-zero (X,Y >= 0 here); in-bounds => already within [0,511].
    const int y_down = (int)Y;
    const int x_down = (int)X;
    const int y_up = min(y_down + 1, H_IN - 1);
    const int x_up = min(x_down + 1, W_IN - 1);

    const float yd = Y - (float)y_down;
    const float yu = Y - (float)y_up;
    const float xd = X - (float)x_down;
    const float xu = X - (float)x_up;

    const float dd = yd * yd + xd * xd;
    const float du = yd * yd + xu * xu;
    const float ud = yu * yu + xd * xd;
    const float uu = yu * yu + xu * xu;
    const float total = ((dd + du) + ud) + uu;

    const float wdd = dd / total;
    const float wdu = du / total;
    const float wud = ud / total;
    const float wuu = uu / total;

    const int o_dd = y_down * W_IN + x_down;
    const int o_du = y_down * W_IN + x_up;
    const int o_ud = y_up * W_IN + x_down;
    const int o_uu = y_up * W_IN + x_up;

    #pragma unroll 4
    for (int bc = 0; bc < IMGS_PER_CHUNK; ++bc) {
        const float g1 = p[o_dd];
        const float g2 = p[o_du];
        const float g3 = p[o_ud];
        const float g4 = p[o_uu];
        *q = ((wdd * g1 + wdu * g2) + wud * g3) + wuu * g4;
        p += IMG;
        q += IMG;
    }
}

extern "C" void kernel_launch(void* const* d_in, const int* in_sizes, int n_in,
                              void* d_out, int out_size, void* d_ws, size_t ws_size,
                              hipStream_t stream)
{
    const float* data = (const float*)d_in[0];
    float* out = (float*)d_out;

    const int threads = 256;
    const int blocks = (NPIX / threads) * NCHUNK;  // 1024 * 8 = 8192
    logpolar_kernel<<<blocks, threads, 0, stream>>>(data, out);
}